// Round 11
// baseline (381.390 us; speedup 1.0000x reference)
//
#include <hip/hip_runtime.h>

typedef __attribute__((ext_vector_type(8))) short short8;
typedef __attribute__((ext_vector_type(4))) float f32x4;
typedef __attribute__((ext_vector_type(4))) unsigned int u32x4;
typedef __attribute__((ext_vector_type(2))) long long2_t;

#define NTOK 4096
#define DIM  256
#define P_STRIDE 72            // P row stride elems (144 B)
#define KS_ROW 272             // fp8 Ks row stride bytes (256 + 16 pad)
#define KS_TILE 17408          // 64 * 272 B
#define KT_TILE 16384          // ushorts per Kt tile (32 KB)
// workspace offsets (bytes)
#define KT_OFF   4456448ull                    // 4*64*KS_TILE
#define PART_OFF 12845056ull                   // + 4*64*32768
#define LSUM_OFF 29622272ull                   // + 2*4*64*64*256*2 (bf16 partials)
#define FLAG_OFF 29753344ull                   // + 2*4*64*64*4 (f32 lsums)

__device__ __forceinline__ unsigned pack2bf(float a, float b) {
  unsigned ua = __builtin_bit_cast(unsigned, a) + 0x8000u;
  unsigned ub = __builtin_bit_cast(unsigned, b) + 0x8000u;
  return __builtin_amdgcn_perm(ub, ua, 0x07060302u);
}
__device__ __forceinline__ unsigned short f2bf(float f) { // RNE
  unsigned u = __builtin_bit_cast(unsigned, f);
  u += 0x7fffu + ((u >> 16) & 1u);
  return (unsigned short)(u >> 16);
}

// ---- prologue: fp8 Ks images (MFMA-permuted rows) + bf16 Kt images -------
__global__ __launch_bounds__(256, 4)
void prep_kernel(const float* __restrict__ X, unsigned char* __restrict__ Ws) {
  unsigned char*  Ksf8 = Ws;
  unsigned short* KtImg = (unsigned short*)(Ws + KT_OFF);
  const int b    = blockIdx.x & 3;
  const int sub  = blockIdx.x >> 2;
  const int t    = sub >> 3;
  const int part = sub & 7;
  const int tid  = threadIdx.x;
  const float* src = X + ((size_t)b * NTOK + t * 64) * DIM;
  unsigned char* dstK = Ksf8 + (size_t)(b * 64 + t) * KS_TILE;
  #pragma unroll
  for (int i = 0; i < 3; ++i) {
    int idx = tid + i * 256;
    if (idx < 544) {
      int rl = idx / 68, w = idx % 68;
      if (w < 64) {
        int r = part * 8 + rl;
        int ds2 = w >> 4, rem = (w & 15) << 2;
        int quad = rem >> 4, rem2 = rem & 15;
        int half = rem2 >> 3, j0 = rem2 & 7;
        int d0 = (2 * ds2 + half) * 32 + quad * 8 + j0;
        const float* s = src + r * DIM + d0;
        int u = 0;
        u = __builtin_amdgcn_cvt_pk_fp8_f32(s[0], s[1], u, false);
        u = __builtin_amdgcn_cvt_pk_fp8_f32(s[2], s[3], u, true);
        *(int*)(dstK + r * KS_ROW + w * 4) = u;
      }
    }
  }
  {
    const int d = tid;
    float f[8];
    #pragma unroll
    for (int i = 0; i < 8; ++i) f[i] = src[(part * 8 + i) * DIM + d];
    union { unsigned u[4]; u32x4 v; } p;
    p.u[0] = pack2bf(f[0], f[1]);
    p.u[1] = pack2bf(f[2], f[3]);
    p.u[2] = pack2bf(f[4], f[5]);
    p.u[3] = pack2bf(f[6], f[7]);
    *(u32x4*)(KtImg + ((size_t)(b * 64 + t)) * KT_TILE + part * 2048 + d * 8) = p.v;
  }
}

// PV: O[s][dt] += P(strips of qh, all 64 keys) x V(d-quarter dq)
__device__ __forceinline__ void pv_step(const unsigned short* __restrict__ pr,
                                        const unsigned short* __restrict__ kt,
                                        f32x4 (&o)[2][4],
                                        int qh, int dq, int quad, int ln) {
  #pragma unroll
  for (int ks = 0; ks < 2; ++ks) {
    const int pos = (ks * 4 + quad) ^ ((ln >> 3) << 1);
    short8 ap[2], bv[4];
    #pragma unroll
    for (int s = 0; s < 2; ++s)
      ap[s] = *(const short8*)(&pr[(qh * 32 + s * 16 + ln) * P_STRIDE + (pos << 3)]);
    const unsigned short* kb = kt + (ks * 4 + quad) * 2048 + (dq * 64 + ln) * 8;
    #pragma unroll
    for (int dt = 0; dt < 4; ++dt) bv[dt] = *(const short8*)(kb + dt * 128);
    #pragma unroll
    for (int s = 0; s < 2; ++s)
      #pragma unroll
      for (int dt = 0; dt < 4; ++dt)
        o[s][dt] = __builtin_amdgcn_mfma_f32_16x16x32_bf16(ap[s], bv[dt], o[s][dt], 0, 0, 0);
  }
}

// ---- flash-attention: split-K, 2 blocks/CU, in-kernel pair merge ---------
__global__ __launch_bounds__(512, 4)
void fa_kernel(unsigned char* __restrict__ Ws, float* __restrict__ Out) {
  __shared__ __align__(16) unsigned char  ksb[2][KS_TILE];      // 34 KB fp8
  __shared__ __align__(16) unsigned short ktb[KT_TILE];         // 32 KB bf16
  __shared__ __align__(16) unsigned short pb[64 * P_STRIDE];    // 9 KB
  __shared__ float lbuf[64][4];                                 // 1 KB
  __shared__ int who;

  const unsigned char*  Ksf8  = Ws;
  const unsigned short* KtImg = (const unsigned short*)(Ws + KT_OFF);

  const int tid  = threadIdx.x;
  const int b    = blockIdx.x & 3;          // XCD-local batch
  const int kh   = (blockIdx.x >> 2) & 1;   // K-half
  const int qblk = blockIdx.x >> 3;         // 0..63
  const int wave = tid >> 6;
  const int lane = tid & 63;
  const int ln   = lane & 15;
  const int quad = lane >> 4;
  const int qh   = wave & 1;    // Q-half (QK + PV strips)
  const int kq   = wave >> 1;   // QK: key-quarter; PV: d-quarter

  const unsigned char*  ksT = Ksf8 + (size_t)(b * 64 + kh * 32) * KS_TILE;
  const unsigned short* ktT = KtImg + (size_t)(b * 64 + kh * 32) * KT_TILE;

  // Q fragments (fp8, permuted rows of tile qblk)
  long aQ[2][8];
  #pragma unroll
  for (int s = 0; s < 2; ++s) {
    const unsigned char* qrow =
        Ksf8 + (size_t)(b * 64 + qblk) * KS_TILE + (qh * 32 + s * 16 + ln) * KS_ROW;
    #pragma unroll
    for (int ds2 = 0; ds2 < 4; ++ds2) {
      long2_t v = *(const long2_t*)(qrow + ds2 * 64 + quad * 16);
      aQ[s][2 * ds2]     = v.x;
      aQ[s][2 * ds2 + 1] = v.y;
    }
  }

  f32x4 o[2][4];
  #pragma unroll
  for (int s = 0; s < 2; ++s)
    #pragma unroll
    for (int dt = 0; dt < 4; ++dt) o[s][dt] = (f32x4)(0.0f);
  float lrow[2][4] = {{0.f,0.f,0.f,0.f},{0.f,0.f,0.f,0.f}};

  const float c2 = 0.0901684400f;  // log2(e)/sqrt(256)
  const int pwPos = ((kq * 2 + (ln >> 3)) ^ ((quad >> 1) << 1)) << 3;
  const int pwCol = ln & 7;

  // prologue: Ks tile 0 of this K-half -> ksb[0]
  #pragma unroll
  for (int i = 0; i < 3; ++i) {
    int idx = wave + i * 8;
    if (idx < 17)
      __builtin_amdgcn_global_load_lds(
          (const __attribute__((address_space(1))) unsigned*)(ksT + idx * 1024 + lane * 16),
          (__attribute__((address_space(3))) unsigned*)(&ksb[0][idx * 1024 + lane * 16]),
          16, 0, 0);
  }

  for (int t = 0; t < 32; ++t) {
    __syncthreads();   // barrier1: Ks(t), Kt(t-1) DMA drained; P(t-1) visible
    if (t > 0) pv_step(pb, ktb, o, qh, kq, quad, ln);
    __syncthreads();   // barrier2: all ktb/pb reads done
    const int buf = t & 1;

    // DMA: Ks(t+1) -> ksb[buf^1] (17 bursts), Kt(t) -> ktb (32 bursts)
    #pragma unroll
    for (int i = 0; i < 7; ++i) {
      int idx = wave + i * 8;
      if (idx < 17) {
        if (t < 31)
          __builtin_amdgcn_global_load_lds(
              (const __attribute__((address_space(1))) unsigned*)
                  (ksT + (size_t)(t + 1) * KS_TILE + idx * 1024 + lane * 16),
              (__attribute__((address_space(3))) unsigned*)(&ksb[buf ^ 1][idx * 1024 + lane * 16]),
              16, 0, 0);
      } else if (idx < 49) {
        int k = idx - 17;
        __builtin_amdgcn_global_load_lds(
            (const __attribute__((address_space(1))) unsigned*)
                ((const unsigned char*)ktT + (size_t)t * 32768 + k * 1024 + lane * 16),
            (__attribute__((address_space(3))) unsigned*)(&ktb[k * 512 + lane * 8]),
            16, 0, 0);
      }
    }

    // --- QK(t): fp8, keys kq*16..+15 of this K-half, both strips ---
    f32x4 sf0 = (f32x4)(0.0f), sf1 = (f32x4)(0.0f);
    {
      const unsigned char* krow = &ksb[buf][(kq * 16 + ln) * KS_ROW];
      #pragma unroll
      for (int ds2 = 0; ds2 < 4; ++ds2) {
        long2_t bk = *(const long2_t*)(krow + ds2 * 64 + quad * 16);
        sf0 = __builtin_amdgcn_mfma_f32_16x16x32_fp8_fp8(aQ[0][2*ds2],   bk.x, sf0, 0, 0, 0);
        sf0 = __builtin_amdgcn_mfma_f32_16x16x32_fp8_fp8(aQ[0][2*ds2+1], bk.y, sf0, 0, 0, 0);
        sf1 = __builtin_amdgcn_mfma_f32_16x16x32_fp8_fp8(aQ[1][2*ds2],   bk.x, sf1, 0, 0, 0);
        sf1 = __builtin_amdgcn_mfma_f32_16x16x32_fp8_fp8(aQ[1][2*ds2+1], bk.y, sf1, 0, 0, 0);
      }
    }
    // --- softmax numerators; packed P store ---
    #pragma unroll
    for (int j = 0; j < 4; ++j) {
      float p0 = __builtin_amdgcn_exp2f(sf0[j] * c2);
      float p1 = __builtin_amdgcn_exp2f(sf1[j] * c2);
      lrow[0][j] += p0;
      lrow[1][j] += p1;
      unsigned q0 = __builtin_bit_cast(unsigned, p0);
      unsigned q1 = __builtin_bit_cast(unsigned, p1);
      unsigned n0 = (unsigned)__builtin_amdgcn_mov_dpp((int)q0, 0xB1, 0xF, 0xF, true);
      unsigned n1 = (unsigned)__builtin_amdgcn_mov_dpp((int)q1, 0xB1, 0xF, 0xF, true);
      if ((ln & 1) == 0) {
        const int r0 = qh * 32 + quad * 4 + j;
        unsigned d0 = pack2bf(__builtin_bit_cast(float, q0), __builtin_bit_cast(float, n0));
        unsigned d1 = pack2bf(__builtin_bit_cast(float, q1), __builtin_bit_cast(float, n1));
        *(unsigned*)(&pb[r0 * P_STRIDE + pwPos + pwCol]) = d0;
        *(unsigned*)(&pb[(r0 + 16) * P_STRIDE + pwPos + pwCol]) = d1;
      }
    }
  }

  __syncthreads();   // Kt(31) drained, P(31) visible
  pv_step(pb, ktb, o, qh, kq, quad, ln);

  // --- l reduce across key-lanes, publish per key-quarter ---
  #pragma unroll
  for (int off = 1; off < 16; off <<= 1)
    #pragma unroll
    for (int s = 0; s < 2; ++s)
      #pragma unroll
      for (int j = 0; j < 4; ++j)
        lrow[s][j] += __shfl_xor(lrow[s][j], off, 64);
  if (ln == 0) {
    #pragma unroll
    for (int s = 0; s < 2; ++s)
      #pragma unroll
      for (int j = 0; j < 4; ++j)
        lbuf[qh * 32 + s * 16 + quad * 4 + j][kq] = lrow[s][j];
  }
  __syncthreads();

  // --- write partials (bf16 O, f32 l) for this K-half ---
  float* lsumAll = (float*)(Ws + LSUM_OFF);
  float* lsumMe  = lsumAll + ((size_t)(kh * 4 + b) * 64 + qblk) * 64;
  if (tid < 64) {
    f32x4 lv = *(const f32x4*)lbuf[tid];
    lsumMe[tid] = lv[0] + lv[1] + lv[2] + lv[3];
  }
  unsigned short* pAll = (unsigned short*)(Ws + PART_OFF);
  unsigned short* pMe  = pAll + ((size_t)(kh * 4 + b) * 64 + qblk) * (64 * 256);
  #pragma unroll
  for (int s = 0; s < 2; ++s)
    #pragma unroll
    for (int dt = 0; dt < 4; ++dt)
      #pragma unroll
      for (int j = 0; j < 4; ++j)
        pMe[(qh * 32 + s * 16 + quad * 4 + j) * 256 + kq * 64 + dt * 16 + ln] = f2bf(o[s][dt][j]);

  __threadfence();
  __syncthreads();
  if (tid == 0)
    who = atomicAdd((int*)(Ws + FLAG_OFF) + (b * 64 + qblk), 1);
  __syncthreads();

  if (who == 1) {  // second arrival merges the pair
    __threadfence();
    const unsigned short* pA = pAll + ((size_t)(0 * 4 + b) * 64 + qblk) * (64 * 256);
    const unsigned short* pB = pAll + ((size_t)(1 * 4 + b) * 64 + qblk) * (64 * 256);
    const float* lA = lsumAll + ((size_t)(0 * 4 + b) * 64 + qblk) * 64;
    const float* lB = lsumAll + ((size_t)(1 * 4 + b) * 64 + qblk) * 64;
    float* outp = Out + ((size_t)b * NTOK + qblk * 64) * DIM;
    #pragma unroll
    for (int c = 0; c < 4; ++c) {
      int idx8 = c * 512 + tid;        // 8-elem chunk id
      int e = idx8 * 8;
      int row = e >> 8;
      u32x4 va = *(const u32x4*)(pA + e);
      u32x4 vb = *(const u32x4*)(pB + e);
      float rl = 1.0f / (lA[row] + lB[row]);
      f32x4 o0, o1;
      #pragma unroll
      for (int k = 0; k < 4; ++k) {
        float a_lo = __builtin_bit_cast(float, va[k] << 16);
        float a_hi = __builtin_bit_cast(float, va[k] & 0xffff0000u);
        float b_lo = __builtin_bit_cast(float, vb[k] << 16);
        float b_hi = __builtin_bit_cast(float, vb[k] & 0xffff0000u);
        float vlo = (a_lo + b_lo) * rl;
        float vhi = (a_hi + b_hi) * rl;
        if (k < 2) { o0[2*k] = vlo; o0[2*k+1] = vhi; }
        else       { o1[2*(k-2)] = vlo; o1[2*(k-2)+1] = vhi; }
      }
      *(f32x4*)(outp + e)     = o0;
      *(f32x4*)(outp + e + 4) = o1;
    }
  }
}

extern "C" void kernel_launch(void* const* d_in, const int* in_sizes, int n_in,
                              void* d_out, int out_size, void* d_ws, size_t ws_size,
                              hipStream_t stream) {
  const float* X = (const float*)d_in[0];       // x: fp32 [4,4096,256]
  float* Out = (float*)d_out;                   // fp32 [4,4096,256]
  unsigned char* Ws = (unsigned char*)d_ws;     // ~29.8 MB
  (void)in_sizes; (void)n_in; (void)out_size; (void)ws_size;
  hipMemsetAsync(Ws + FLAG_OFF, 0, 1024, stream);          // pair flags
  hipLaunchKernelGGL(prep_kernel, dim3(2048), dim3(256), 0, stream, X, Ws);
  hipLaunchKernelGGL(fa_kernel, dim3(512), dim3(512), 0, stream, Ws, Out);
}

// Round 12
// 182.489 us; speedup vs baseline: 2.0899x; 2.0899x over previous
//
#include <hip/hip_runtime.h>

typedef __attribute__((ext_vector_type(8))) short short8;
typedef __attribute__((ext_vector_type(4))) float f32x4;
typedef __attribute__((ext_vector_type(4))) unsigned int u32x4;
typedef __attribute__((ext_vector_type(2))) long long2_t;

#define NTOK 4096
#define DIM  256
#define PSTR 40                 // P row stride elems (80 B)
#define KS_SUB 8192             // bytes per fp8 Ks subtile: 32 rows x 256 B
#define KT_SUB 8192             // ushorts per Kt subtile (16 KB): [4 kb][256 d][8 tok]
#define KT_OFF 4194304ull       // 4*128*KS_SUB bytes

__device__ __forceinline__ unsigned pack2bf(float a, float b) {
  unsigned ua = __builtin_bit_cast(unsigned, a) + 0x8000u;
  unsigned ub = __builtin_bit_cast(unsigned, b) + 0x8000u;
  return __builtin_amdgcn_perm(ub, ua, 0x07060302u);
}

// ---- prologue: fp8 Ks subtiles (permuted rows, chunk-swizzled) + bf16 Kt -
// Ks row: chunk c (16B) holds d-range of (ds2=c>>2, quad=c&3); stored at c^(r&15).
__global__ __launch_bounds__(256, 4)
void prep_kernel(const float* __restrict__ X, unsigned char* __restrict__ Ws) {
  unsigned char*  Ksf8 = Ws;
  unsigned short* KtImg = (unsigned short*)(Ws + KT_OFF);
  const int b    = blockIdx.x & 3;
  const int sub  = blockIdx.x >> 2;   // 0..511
  const int st   = sub >> 2;          // 32-token subtile 0..127
  const int part = sub & 3;           // 8-token group
  const int tid  = threadIdx.x;
  const float* src = X + ((size_t)b * NTOK + st * 32) * DIM;
  unsigned char* dstK = Ksf8 + (size_t)(b * 128 + st) * KS_SUB;
  // Ks: rows part*8..+7, 64 dwords/row -> 512 dwords, 2/thread
  #pragma unroll
  for (int i = 0; i < 2; ++i) {
    int idx = tid + i * 256;          // 0..511
    int rl = idx >> 6, w = idx & 63;
    int r = part * 8 + rl;
    int ds2 = w >> 4, rem4 = (w & 15) << 2;
    int quad = rem4 >> 4, rem2 = rem4 & 15;
    int half = rem2 >> 3, j0 = rem2 & 7;
    int d0 = (2 * ds2 + half) * 32 + quad * 8 + j0;
    const float* s = src + r * DIM + d0;
    int u = 0;
    u = __builtin_amdgcn_cvt_pk_fp8_f32(s[0], s[1], u, false);
    u = __builtin_amdgcn_cvt_pk_fp8_f32(s[2], s[3], u, true);
    int c = w >> 2, dw = w & 3;
    *(int*)(dstK + r * 256 + ((c ^ (r & 15)) << 4) + dw * 4) = u;
  }
  // Kt: kb-block = part; thread = d
  {
    const int d = tid;
    float f[8];
    #pragma unroll
    for (int i = 0; i < 8; ++i) f[i] = src[(part * 8 + i) * DIM + d];
    union { unsigned u[4]; u32x4 v; } p;
    p.u[0] = pack2bf(f[0], f[1]);
    p.u[1] = pack2bf(f[2], f[3]);
    p.u[2] = pack2bf(f[4], f[5]);
    p.u[3] = pack2bf(f[6], f[7]);
    *(u32x4*)(KtImg + (size_t)(b * 128 + st) * KT_SUB + part * 2048 + d * 8) = p.v;
  }
}

// PV: o[s][dt] += P(strip s, 32 keys) x V(d-quarter dq); K=32 in one MFMA step
__device__ __forceinline__ void pv_step(const unsigned short* __restrict__ pr,
                                        const unsigned short* __restrict__ kt,
                                        f32x4 (&o)[2][4],
                                        int dq, int quad, int ln) {
  const int pos = quad ^ ((ln >> 3) << 1);   // matches write swizzle: r>>3&1 == ln>>3
  short8 ap[2], bv[4];
  #pragma unroll
  for (int s = 0; s < 2; ++s)
    ap[s] = *(const short8*)(&pr[(s * 16 + ln) * PSTR + (pos << 3)]);
  const unsigned short* kbp = kt + quad * 2048 + (dq * 64 + ln) * 8;
  #pragma unroll
  for (int dt = 0; dt < 4; ++dt) bv[dt] = *(const short8*)(kbp + dt * 128);
  #pragma unroll
  for (int s = 0; s < 2; ++s)
    #pragma unroll
    for (int dt = 0; dt < 4; ++dt)
      o[s][dt] = __builtin_amdgcn_mfma_f32_16x16x32_bf16(ap[s], bv[dt], o[s][dt], 0, 0, 0);
}

// ---- flash-attention: Q-split (32 rows/block), 2 blocks/CU, 1 barrier/iter
__global__ __launch_bounds__(512, 4)
void fa_kernel(const unsigned char* __restrict__ Ws, float* __restrict__ Out) {
  __shared__ __align__(16) unsigned char  ksb[2][KS_SUB];     // 16 KB fp8
  __shared__ __align__(16) unsigned short ktb[2][KT_SUB];     // 32 KB bf16
  __shared__ __align__(16) unsigned short pb[2][32 * PSTR];   // 5 KB
  __shared__ float lbuf[32][2];                               // 256 B

  const unsigned char* Ksf8 = Ws;

  const int tid  = threadIdx.x;
  const int b    = blockIdx.x & 3;     // batch -> XCD-ish locality
  const int qs   = blockIdx.x >> 2;    // 32-row Q-block 0..127
  const int wave = tid >> 6;
  const int lane = tid & 63;
  const int ln   = lane & 15;
  const int quad = lane >> 4;
  const bool isQK = wave < 4;
  const int sh = wave & 1;             // QK: strip (16 rows)
  const int kk = (wave >> 1) & 1;      // QK: key-half (16 keys)
  const int dq = wave & 3;             // PV: d-quarter (64 cols)

  const unsigned char* ksT = Ksf8 + (size_t)(b * 128) * KS_SUB;
  const unsigned char* ktT = Ws + KT_OFF + (size_t)(b * 128) * (KT_SUB * 2);

  // Q fragments (QK waves): rows qs*32 + sh*16 + ln, from permuted fp8 image
  long aQ[8];
  if (isQK) {
    const unsigned char* qrow = ksT + (size_t)qs * KS_SUB + (sh * 16 + ln) * 256;
    #pragma unroll
    for (int ds2 = 0; ds2 < 4; ++ds2) {
      long2_t v = *(const long2_t*)(qrow + (((ds2 * 4 + quad) ^ ln) << 4));
      aQ[2 * ds2]     = v.x;
      aQ[2 * ds2 + 1] = v.y;
    }
  }

  f32x4 o[2][4];
  #pragma unroll
  for (int s = 0; s < 2; ++s)
    #pragma unroll
    for (int dt = 0; dt < 4; ++dt) o[s][dt] = (f32x4)(0.0f);
  float lrow[4] = {0.f, 0.f, 0.f, 0.f};

  const float c2 = 0.0901684400f;  // log2(e)/sqrt(256)

  // prologue: Ks(0) -> ksb[0], one burst per wave
  __builtin_amdgcn_global_load_lds(
      (const __attribute__((address_space(1))) unsigned*)(ksT + wave * 1024 + lane * 16),
      (__attribute__((address_space(3))) unsigned*)(&ksb[0][wave * 1024 + lane * 16]),
      16, 0, 0);

  for (int t = 0; t < 128; ++t) {
    __syncthreads();   // drains all DMA issued last iter; Ks(t)/Kt(t-1)/P(t-1) ready
    const int buf = t & 1;

    // DMA with full-iteration slack: Ks(t+1) -> ksb[buf^1], Kt(t) -> ktb[buf]
    if (t < 127)
      __builtin_amdgcn_global_load_lds(
          (const __attribute__((address_space(1))) unsigned*)
              (ksT + (size_t)(t + 1) * KS_SUB + wave * 1024 + lane * 16),
          (__attribute__((address_space(3))) unsigned*)(&ksb[buf ^ 1][wave * 1024 + lane * 16]),
          16, 0, 0);
    #pragma unroll
    for (int i = 0; i < 2; ++i) {
      int kb = wave * 2 + i;
      __builtin_amdgcn_global_load_lds(
          (const __attribute__((address_space(1))) unsigned*)
              (ktT + (size_t)t * 16384 + kb * 1024 + lane * 16),
          (__attribute__((address_space(3))) unsigned*)(&ktb[buf][kb * 512 + lane * 8]),
          16, 0, 0);
    }

    if (isQK) {
      // --- QK(t): strip sh x keys kk*16..+15, K=256 fp8 ---
      f32x4 sf = (f32x4)(0.0f);
      const unsigned char* krow = &ksb[buf][(kk * 16 + ln) * 256];
      #pragma unroll
      for (int ds2 = 0; ds2 < 4; ++ds2) {
        long2_t bk = *(const long2_t*)(krow + (((ds2 * 4 + quad) ^ ln) << 4));
        sf = __builtin_amdgcn_mfma_f32_16x16x32_fp8_fp8(aQ[2 * ds2],     bk.x, sf, 0, 0, 0);
        sf = __builtin_amdgcn_mfma_f32_16x16x32_fp8_fp8(aQ[2 * ds2 + 1], bk.y, sf, 0, 0, 0);
      }
      // softmax numerators; packed P store
      unsigned short* pw = pb[buf];
      #pragma unroll
      for (int j = 0; j < 4; ++j) {
        float p = __builtin_amdgcn_exp2f(sf[j] * c2);
        lrow[j] += p;
        unsigned q = __builtin_bit_cast(unsigned, p);
        unsigned n = (unsigned)__builtin_amdgcn_mov_dpp((int)q, 0xB1, 0xF, 0xF, true);
        if ((ln & 1) == 0) {
          const int r0 = sh * 16 + quad * 4 + j;
          const int kc = kk * 2 + (ln >> 3);
          const int pos = kc ^ (((r0 >> 3) & 1) << 1);
          unsigned d0 = pack2bf(__builtin_bit_cast(float, q), __builtin_bit_cast(float, n));
          *(unsigned*)(&pw[r0 * PSTR + (pos << 3) + (ln & 7)]) = d0;
        }
      }
    } else {
      // --- PV(t-1) ---
      if (t > 0) pv_step(pb[buf ^ 1], ktb[buf ^ 1], o, dq, quad, ln);
    }
  }

  __syncthreads();   // P(127), Kt(127) resident (both in slot 1)
  if (!isQK) pv_step(pb[1], ktb[1], o, dq, quad, ln);

  // --- l publish (QK waves), divide + store (PV waves) ---
  if (isQK) {
    #pragma unroll
    for (int off = 1; off < 16; off <<= 1)
      #pragma unroll
      for (int j = 0; j < 4; ++j)
        lrow[j] += __shfl_xor(lrow[j], off, 64);
    if (ln == 0) {
      #pragma unroll
      for (int j = 0; j < 4; ++j)
        lbuf[sh * 16 + quad * 4 + j][kk] = lrow[j];
    }
  }
  __syncthreads();
  if (!isQK) {
    float* outp = Out + ((size_t)b * NTOK + qs * 32) * DIM + dq * 64;
    #pragma unroll
    for (int s = 0; s < 2; ++s) {
      #pragma unroll
      for (int j = 0; j < 4; ++j) {
        const int row = s * 16 + quad * 4 + j;
        const float rl = 1.0f / (lbuf[row][0] + lbuf[row][1]);
        #pragma unroll
        for (int dt = 0; dt < 4; ++dt)
          outp[(size_t)row * DIM + dt * 16 + ln] = o[s][dt][j] * rl;
      }
    }
  }
}

extern "C" void kernel_launch(void* const* d_in, const int* in_sizes, int n_in,
                              void* d_out, int out_size, void* d_ws, size_t ws_size,
                              hipStream_t stream) {
  const float* X = (const float*)d_in[0];       // x: fp32 [4,4096,256]
  float* Out = (float*)d_out;                   // fp32 [4,4096,256]
  unsigned char* Ws = (unsigned char*)d_ws;     // 4 MB fp8 Ks + 8 MB bf16 Kt
  (void)in_sizes; (void)n_in; (void)out_size; (void)ws_size;
  hipLaunchKernelGGL(prep_kernel, dim3(2048), dim3(256), 0, stream, X, Ws);
  hipLaunchKernelGGL(fa_kernel, dim3(512), dim3(512), 0, stream, Ws, Out);
}